// Round 8
// baseline (322.001 us; speedup 1.0000x reference)
//
#include <hip/hip_runtime.h>

typedef __attribute__((ext_vector_type(8))) short short8b;
typedef __attribute__((ext_vector_type(4))) float f32x4;

#define NEG_SENTINEL (-1e30f)

// ---------------- workspace layout (float units) ----------------
constexpr int C_OFF    = 0;        // 2*4096 colsums (zeroed)
constexpr int C2_OFF   = 8192;     // 2*4096 c2 (zeroed)
constexpr int SC_OFF   = 16384;    // scalar (zeroed)
constexpr int FLAG_I   = 16390;    // int index: 1 = bf16 inputs, 0 = fp32
constexpr int ZERO_N   = 16448;    // floats zeroed by memset
constexpr int V_OFF    = 16448;    // 20*128 projected weight vectors
constexpr int NP_OFF   = 19008;    // 20*4096 node projections
constexpr int SRC_OFF  = 100928;   // 2*(4096 src + 4096 dst)
constexpr int RM_OFF   = 117312;   // 2*4096 row max
constexpr int RS_OFF   = 125504;   // 2*4096 row sum
constexpr int NNZ_OFF  = 133696;   // 2*4096 ints
constexpr int CCI_OFF  = 141888;   // 2*4096*128 ushort cols (524288 floats)
constexpr int XBT_OFF  = 666176;   // x^T bf16 [128][4096] (262144 floats)
constexpr int TP_OFF   = 928320;   // 8 * 524288 T partials (16 MB)
constexpr int BM_OFF   = 5122624;  // 2*4096*512 B bitmasks (1048576 floats = 4 MB)
// end: 6171200 floats ≈ 23.5 MB

__device__ __forceinline__ unsigned short f2bf(float f) {
  unsigned int u = __float_as_uint(f);
  u += 0x7FFFu + ((u >> 16) & 1u);
  return (unsigned short)(u >> 16);
}
__device__ __forceinline__ float bf2f(unsigned short b) {
  return __uint_as_float(((unsigned int)b) << 16);
}
__device__ __forceinline__ float scrub(float v) {
  unsigned int u = __float_as_uint(v);
  return ((u & 0x7F800000u) == 0x7F800000u) ? 0.f : v;
}

// 20 projected vectors + integrated dtype detection.
__global__ __launch_bounds__(128) void k_vvec(const void* __restrict__ xin,
                                              const void* __restrict__ w_irr,
                                              const void* __restrict__ w_sol,
                                              const void* __restrict__ att_irr,
                                              const void* __restrict__ att_sol,
                                              int* __restrict__ flagp,
                                              float* __restrict__ vvec) {
  __shared__ int sdet[128];
  int t = threadIdx.x;
  unsigned int ef = (((const unsigned int*)xin)[t] >> 7) & 0xFFu;
  sdet[t] = (ef >= 100u && ef <= 150u) ? 1 : 0;
  __syncthreads();
  for (int d = 64; d > 0; d >>= 1) { if (t < d) sdet[t] += sdet[t + d]; __syncthreads(); }
  int f = (sdet[0] >= 96) ? 1 : 0;
  if (blockIdx.x == 0 && t == 0) *flagp = f;
  int bx = blockIdx.x;  // b*10 + j*5 + tt
  int b = bx / 10, rem = bx % 10, j = rem / 5, tt = rem % 5;
  const void* Wv = (b == 0 ? w_irr : w_sol);
  const void* Av = (b == 0 ? att_irr : att_sol);
  int i = t;
  float s = 0.f;
  if (f) {
    const unsigned short* Wr = (const unsigned short*)Wv + (size_t)j * 16384 + (size_t)i * 128;
    const unsigned short* Ar = (const unsigned short*)Av + tt * 128;
    for (int o = 0; o < 128; o += 8) {
      uint4 wq = *(const uint4*)(Wr + o);
      unsigned int ww[4] = {wq.x, wq.y, wq.z, wq.w};
      float cf[8];
      if (tt < 4) {
        uint4 aq = *(const uint4*)(Ar + o);
        unsigned int aa[4] = {aq.x, aq.y, aq.z, aq.w};
#pragma unroll
        for (int u = 0; u < 4; ++u) {
          cf[2 * u] = bf2f((unsigned short)(aa[u] & 0xFFFFu));
          cf[2 * u + 1] = bf2f((unsigned short)(aa[u] >> 16));
        }
      } else {
#pragma unroll
        for (int e = 0; e < 8; ++e) cf[e] = 1.0f;
      }
#pragma unroll
      for (int u = 0; u < 4; ++u) {
        s += bf2f((unsigned short)(ww[u] & 0xFFFFu)) * cf[2 * u];
        s += bf2f((unsigned short)(ww[u] >> 16)) * cf[2 * u + 1];
      }
    }
  } else {
    const float* Wr = (const float*)Wv + (size_t)j * 16384 + (size_t)i * 128;
    const float* Ar = (const float*)Av + tt * 128;
    for (int o = 0; o < 128; o += 4) {
      float4 wq = *(const float4*)(Wr + o);
      float4 aq = {1.f, 1.f, 1.f, 1.f};
      if (tt < 4) aq = *(const float4*)(Ar + o);
      s += wq.x * aq.x + wq.y * aq.y + wq.z * aq.z + wq.w * aq.w;
    }
  }
  vvec[bx * 128 + i] = s;
}

// fused: decode x -> LDS; emit xbT (bf16 transpose), np (20 dots/node), src/dst
__global__ __launch_bounds__(256) void k_prep(const void* __restrict__ xin,
                                              const int* __restrict__ flag,
                                              const float* __restrict__ vvec,
                                              unsigned short* __restrict__ xbT,
                                              float* __restrict__ np,
                                              float* __restrict__ srcdst) {
  __shared__ __align__(16) float ldsx[64 * 130];
  __shared__ __align__(16) float ldsv[2560];
  __shared__ float ldsp[4 * 1280];
  __shared__ float npl[1280];
  int f = *flag;
  int t = threadIdx.x, nb = blockIdx.x * 64;
  for (int q = 0; q < 16; ++q) {
    int idx = q * 256 + t;
    int row = idx >> 6, cp = idx & 63;
    float vx, vy;
    if (f) {
      unsigned int u = ((const unsigned int*)xin)[(size_t)(nb + row) * 64 + cp];
      vx = bf2f((unsigned short)(u & 0xFFFFu));
      vy = bf2f((unsigned short)(u >> 16));
    } else {
      float2 v = ((const float2*)xin)[(size_t)(nb + row) * 64 + cp];
      vx = v.x; vy = v.y;
    }
    ldsx[row * 130 + cp * 2] = vx;
    ldsx[row * 130 + cp * 2 + 1] = vy;
  }
  for (int q = 0; q < 10; ++q) { int idx = q * 256 + t; ldsv[idx] = vvec[idx]; }
  __syncthreads();
  for (int q = 0; q < 32; ++q) {
    int idx = q * 256 + t;
    int c = idx >> 6, n = idx & 63;
    xbT[(size_t)c * 4096 + nb + n] = f2bf(ldsx[n * 130 + c]);
  }
  int row = t & 63, qq = t >> 6, i0 = qq * 32;
  float acc[20];
#pragma unroll
  for (int k = 0; k < 20; ++k) acc[k] = 0.f;
  for (int i = i0; i < i0 + 32; i += 2) {
    float2 xv = *(const float2*)&ldsx[row * 130 + i];
#pragma unroll
    for (int k = 0; k < 20; ++k) {
      float2 vk = *(const float2*)&ldsv[k * 128 + i];
      acc[k] += xv.x * vk.x + xv.y * vk.y;
    }
  }
#pragma unroll
  for (int k = 0; k < 20; ++k) ldsp[qq * 1280 + row * 20 + k] = acc[k];
  __syncthreads();
  for (int rep = 0; rep < 5; ++rep) {
    int idx = rep * 256 + t;
    int k = idx >> 6, rr = idx & 63;
    float s = ldsp[rr * 20 + k] + ldsp[1280 + rr * 20 + k] +
              ldsp[2560 + rr * 20 + k] + ldsp[3840 + rr * 20 + k];
    npl[k * 64 + rr] = s;
    np[(size_t)k * 4096 + nb + rr] = s;
  }
  __syncthreads();
  {
    int b = t >> 7, j = (t >> 6) & 1, kind = (t >> 5) & 1, q = t & 31;
    int bl = q * 2;
    int r = j * 2048 + (nb >> 1) + q;
    int kidx = b * 10 + j * 5 + kind * 2;
    float val = npl[kidx * 64 + bl] + npl[(kidx + 1) * 64 + bl + 1];
    srcdst[b * 8192 + kind * 4096 + r] = val;
  }
}

// streaming bitmask compression: thread -> 8 cols -> 1 byte. Zero dep chains.
// byte j of row r covers cols [j*8, j*8+8); bit k = col j*8+k nonzero.
__global__ __launch_bounds__(256) void k_mask(const void* __restrict__ Ldown,
                                              const void* __restrict__ Lup,
                                              const int* __restrict__ flag,
                                              unsigned char* __restrict__ bm) {
  int f = *flag;
  int b = blockIdx.y;
  const void* mask = b ? Lup : Ldown;
  int idx = blockIdx.x * 256 + threadIdx.x;  // 0 .. 2M-1 (row*512 + j)
  unsigned int byte = 0;
  if (f) {
    uint4 v = ((const uint4*)mask)[idx];  // 8 halfwords
    unsigned int wv[4] = {v.x, v.y, v.z, v.w};
#pragma unroll
    for (int u = 0; u < 4; ++u) {
      byte |= ((wv[u] & 0xFFFFu) != 0u ? 1u : 0u) << (2 * u);
      byte |= ((wv[u] >> 16) != 0u ? 1u : 0u) << (2 * u + 1);
    }
  } else {
    const uint4* p = (const uint4*)mask + (size_t)idx * 2;  // 8 floats
    uint4 v0 = p[0], v1 = p[1];
    unsigned int wv[8] = {v0.x, v0.y, v0.z, v0.w, v1.x, v1.y, v1.z, v1.w};
#pragma unroll
    for (int u = 0; u < 8; ++u) byte |= (wv[u] != 0u ? 1u : 0u) << u;
  }
  bm[(size_t)b * 2097152 + idx] = (unsigned char)byte;
}

// wave-per-row softmax from compressed bitmask: lane l owns cols [l*64,l*64+64)
// (one 8B qword load), prefix-sum for CSR slots, e cached in regs for pass 2.
__global__ __launch_bounds__(256) void k_soft(float* __restrict__ ws) {
  const unsigned char* bm = (const unsigned char*)(ws + BM_OFF);
  int b = blockIdx.y, t = threadIdx.x;
  int wid = t >> 6, l = t & 63;
  int r = blockIdx.x * 4 + wid;
  unsigned short* cci = (unsigned short*)(ws + CCI_OFF) + (size_t)(b * 4096 + r) * 128;
  unsigned long long hm =
      ((const unsigned long long*)(bm + ((size_t)b * 4096 + r) * 512))[l];
  int cnt = __popcll(hm);
  int pre = cnt;
  for (int d = 1; d < 64; d <<= 1) {
    int o = __shfl_up(pre, d);
    if (l >= d) pre += o;
  }
  int base = pre - cnt;
  int nz = __shfl(pre, 63);
  if (l == 0) ((int*)ws)[NNZ_OFF + b * 4096 + r] = min(nz, 128);
  const float* srcp = ws + SRC_OFF + b * 8192;
  const float* dstp = srcp + 4096;
  float srcr = srcp[r];
  // pass 1: gather + online softmax, cache e values (<=6 hits/lane typical)
  float ev[6];
  int nh = 0;
  float mx = NEG_SENTINEL, sm = 0.f;
  unsigned long long mm = hm;
  while (mm) {
    int bit = __builtin_ctzll(mm); mm &= mm - 1;
    int m = l * 64 + bit;
    float e = srcr + dstp[m];
    e = (e >= 0.f) ? e : 0.01f * e;
    if (nh < 6) ev[nh] = e;
    ++nh;
    if (e > mx) { sm = sm * __expf(mx - e) + 1.f; mx = e; }
    else        { sm += __expf(e - mx); }
  }
  for (int d = 1; d < 64; d <<= 1) {
    float om = __shfl_xor(mx, d);
    float os = __shfl_xor(sm, d);
    float M = fmaxf(mx, om);
    sm = sm * __expf(mx - M) + os * __expf(om - M);
    mx = M;
  }
  if (l == 0) {
    ws[RM_OFF + b * 4096 + r] = mx;
    ws[RS_OFF + b * 4096 + r] = sm;
  }
  float inv = 1.0f / sm;
  // pass 2: CSR store + colsum scatter (no gathers; ev cached)
  int slot = base, i = 0;
  mm = hm;
  while (mm) {
    int bit = __builtin_ctzll(mm); mm &= mm - 1;
    int m = l * 64 + bit;
    if (slot < 128) cci[slot] = (unsigned short)m;
    ++slot;
    float e;
    if (i < 6) e = ev[i];
    else { e = srcr + dstp[m]; e = (e >= 0.f) ? e : 0.01f * e; }
    ++i;
    atomicAdd(&ws[C_OFF + b * 4096 + m], __expf(e - mx) * inv);
  }
}

__device__ __forceinline__ float alpha_of(const float* ws, int b, int r, int m) {
  const float* srcp = ws + SRC_OFF + b * 8192;
  float e = srcp[r] + srcp[4096 + m];
  e = (e >= 0.f) ? e : 0.01f * e;
  return __expf(e - ws[RM_OFF + b * 4096 + r]) / ws[RS_OFF + b * 4096 + r];
}

// c2[m] += c[r]*alpha[r,m]
__global__ __launch_bounds__(256) void k_c2(float* __restrict__ ws) {
  int b = blockIdx.y;
  int s = blockIdx.x * 256 + threadIdx.x;
  int r = s >> 7, k = s & 127;
  int nz = ((const int*)ws)[NNZ_OFF + b * 4096 + r];
  if (k < nz) {
    int m = ((const unsigned short*)(ws + CCI_OFF))[(size_t)(b * 4096 + r) * 128 + k];
    atomicAdd(&ws[C2_OFF + b * 4096 + m], ws[C_OFF + b * 4096 + r] * alpha_of(ws, b, r, m));
  }
}

__global__ __launch_bounds__(256) void k_scalar(float* __restrict__ ws) {
  int b = blockIdx.x, t = threadIdx.x;
  const float* cb  = ws + C_OFF  + b * 4096;
  const float* c2b = ws + C2_OFF + b * 4096;
  const float* hr0 = ws + NP_OFF + (b * 10 + 4) * 4096;
  const float* hr1 = ws + NP_OFF + (b * 10 + 9) * 4096;
  double acc = 0.0;
  for (int m = t; m < 4096; m += 256)
    acc += (double)scrub(cb[m]) * (double)scrub(hr0[m]) +
           (double)scrub(c2b[m]) * (double)scrub(hr1[m]);
  __shared__ double sd[256];
  sd[t] = acc;
  __syncthreads();
  for (int s = 128; s > 0; s >>= 1) { if (t < s) sd[t] += sd[t + s]; __syncthreads(); }
  if (t == 0) atomicAdd(&ws[SC_OFF], (float)sd[0]);
}

// T = P @ x: 512 blocks (64 M-tiles x 8 K-splits), pipelined, partial stores
__global__ __launch_bounds__(256) void k_gemm1(const void* __restrict__ P,
                                               const unsigned short* __restrict__ xbT,
                                               const int* __restrict__ flag,
                                               float* __restrict__ TP) {
  __shared__ __align__(16) unsigned short a_lds[64 * 40];
  __shared__ __align__(16) unsigned short b_lds[128 * 40];
  int f = *flag;
  const int mt = blockIdx.x & 63, ks = blockIdx.x >> 6;
  const int mb = mt * 64;
  const int t = threadIdx.x;
  const int w = t >> 6, l = t & 63, quad = l >> 4, lr = l & 15;
  f32x4 acc[8] = {};
  const int arow = t >> 2, akq = (t & 3) << 3;
  const int bn = t >> 1, bh = (t & 1) << 4;
  const int k0 = ks * 512;
  uint4 aU, bU0, bU1;
#define LOADT(IT)                                                              \
  {                                                                            \
    const int kb = k0 + (IT) * 32;                                             \
    if (f) {                                                                   \
      aU = *(const uint4*)((const unsigned short*)P +                          \
                           (size_t)(mb + arow) * 4096 + kb + akq);             \
    } else {                                                                   \
      const float* pa = (const float*)P + (size_t)(mb + arow) * 4096 + kb + akq; \
      float4 f0 = *(const float4*)pa;                                          \
      float4 f1 = *(const float4*)(pa + 4);                                    \
      unsigned short u[8] = {f2bf(f0.x), f2bf(f0.y), f2bf(f0.z), f2bf(f0.w),   \
                             f2bf(f1.x), f2bf(f1.y), f2bf(f1.z), f2bf(f1.w)};  \
      aU = *(const uint4*)u;                                                   \
    }                                                                          \
    const unsigned short* src = xbT + (size_t)bn * 4096 + kb + bh;             \
    bU0 = *(const uint4*)src;                                                  \
    bU1 = *(const uint4*)(src + 8);                                            \
  }
  LOADT(0);
  for (int it = 0; it < 16; ++it) {
    *(uint4*)&a_lds[arow * 40 + akq] = aU;
    *(uint4*)&b_lds[bn * 40 + bh] = bU0;
    *(uint4*)&b_lds[bn * 40 + bh + 8] = bU1;
    __syncthreads();
    if (it < 15) LOADT(it + 1);
    short8b af = *(short8b*)&a_lds[(w * 16 + lr) * 40 + quad * 8];
#pragma unroll
    for (int nt = 0; nt < 8; ++nt) {
      short8b bf = *(short8b*)&b_lds[(nt * 16 + lr) * 40 + quad * 8];
      acc[nt] = __builtin_amdgcn_mfma_f32_16x16x32_bf16(af, bf, acc[nt], 0, 0, 0);
    }
    if (it < 15) __syncthreads();
  }
#undef LOADT
  float* Tp = TP + (size_t)ks * 524288;
#pragma unroll
  for (int nt = 0; nt < 8; ++nt)
#pragma unroll
    for (int rr = 0; rr < 4; ++rr) {
      int row = mb + w * 16 + quad * 4 + rr;
      int col = nt * 16 + lr;
      Tp[(size_t)row * 128 + col] = acc[nt][rr];
    }
}

// out = scalar + (sum of 8 T partials) @ W_har; 256 blocks x 16 rows
__global__ __launch_bounds__(256) void k_gemm2(const float* __restrict__ TP,
                                               const void* __restrict__ W,
                                               const float* __restrict__ ws,
                                               void* __restrict__ outv) {
  __shared__ float tl[16 * 128];
  int f = ((const int*)ws)[FLAG_I];
  int t = threadIdx.x;
  int rb = blockIdx.x * 16;
  for (int q = 0; q < 2; ++q) {
    int vi = q * 256 + t;
    size_t base = (size_t)rb * 128 + (size_t)vi * 4;
    float4 s = {0.f, 0.f, 0.f, 0.f};
#pragma unroll
    for (int p = 0; p < 8; ++p) {
      float4 v = *(const float4*)&TP[(size_t)p * 524288 + base];
      s.x += v.x; s.y += v.y; s.z += v.z; s.w += v.w;
    }
    *(float4*)&tl[vi * 4] = s;
  }
  __syncthreads();
  int col = t & 127, rg = t >> 7;
  int r0 = rg * 8;
  float acc[8] = {};
  for (int k = 0; k < 128; k += 4) {
    float w0, w1, w2, w3;
    if (f) {
      const unsigned short* W16 = (const unsigned short*)W;
      w0 = bf2f(W16[(k + 0) * 128 + col]); w1 = bf2f(W16[(k + 1) * 128 + col]);
      w2 = bf2f(W16[(k + 2) * 128 + col]); w3 = bf2f(W16[(k + 3) * 128 + col]);
    } else {
      const float* W32 = (const float*)W;
      w0 = W32[(k + 0) * 128 + col]; w1 = W32[(k + 1) * 128 + col];
      w2 = W32[(k + 2) * 128 + col]; w3 = W32[(k + 3) * 128 + col];
    }
#pragma unroll
    for (int rr = 0; rr < 8; ++rr) {
      float4 tv = *(const float4*)&tl[(r0 + rr) * 128 + k];
      acc[rr] += tv.x * w0 + tv.y * w1 + tv.z * w2 + tv.w * w3;
    }
  }
  float s = scrub(ws[SC_OFF]);
#pragma unroll
  for (int rr = 0; rr < 8; ++rr) {
    size_t oi = (size_t)(rb + r0 + rr) * 128 + col;
    float v = s + acc[rr];
    if (f) ((unsigned short*)outv)[oi] = f2bf(v);
    else   ((float*)outv)[oi] = v;
  }
}

extern "C" void kernel_launch(void* const* d_in, const int* in_sizes, int n_in,
                              void* d_out, int out_size, void* d_ws, size_t ws_size,
                              hipStream_t stream) {
  const void* x       = d_in[0];
  const void* Lup     = d_in[1];
  const void* Ldown   = d_in[2];
  const void* P       = d_in[3];
  const void* w_irr   = d_in[4];
  const void* w_sol   = d_in[5];
  const void* w_har   = d_in[6];
  const void* att_irr = d_in[7];
  const void* att_sol = d_in[8];
  float* ws = (float*)d_ws;

  hipMemsetAsync(d_ws, 0, (size_t)ZERO_N * sizeof(float), stream);
  k_vvec  <<<20, 128, 0, stream>>>(x, w_irr, w_sol, att_irr, att_sol,
                                   (int*)ws + FLAG_I, ws + V_OFF);
  k_prep  <<<64, 256, 0, stream>>>(x, (int*)ws + FLAG_I, ws + V_OFF,
                                   (unsigned short*)(ws + XBT_OFF), ws + NP_OFF,
                                   ws + SRC_OFF);
  k_gemm1 <<<512, 256, 0, stream>>>(P, (const unsigned short*)(ws + XBT_OFF),
                                    (int*)ws + FLAG_I, ws + TP_OFF);
  k_mask  <<<dim3(8192, 2), 256, 0, stream>>>(Ldown, Lup, (int*)ws + FLAG_I,
                                              (unsigned char*)(ws + BM_OFF));
  k_soft  <<<dim3(1024, 2), 256, 0, stream>>>(ws);
  k_c2    <<<dim3(2048, 2), 256, 0, stream>>>(ws);
  k_scalar<<<2, 256, 0, stream>>>(ws);
  k_gemm2 <<<256, 256, 0, stream>>>(ws + TP_OFF, w_har, ws, d_out);
}

// Round 9
// 320.804 us; speedup vs baseline: 1.0037x; 1.0037x over previous
//
#include <hip/hip_runtime.h>

typedef __attribute__((ext_vector_type(8))) short short8b;
typedef __attribute__((ext_vector_type(4))) float f32x4;

#define NEG_SENTINEL (-1e30f)

// ---------------- workspace layout (float units) ----------------
constexpr int C_OFF    = 0;        // 2*4096 colsums (zeroed)
constexpr int C2_OFF   = 8192;     // 2*4096 c2 (zeroed)
constexpr int SC_OFF   = 16384;    // scalar (zeroed)
constexpr int FLAG_I   = 16390;    // int index: 1 = bf16 inputs, 0 = fp32
constexpr int ZERO_N   = 16448;    // floats zeroed by memset
constexpr int V_OFF    = 16448;    // 20*128 projected weight vectors
constexpr int NP_OFF   = 19008;    // 20*4096 node projections
constexpr int SRC_OFF  = 100928;   // 2*(4096 src + 4096 dst)
constexpr int RM_OFF   = 117312;   // 2*4096 row max
constexpr int RS_OFF   = 125504;   // 2*4096 row sum
constexpr int XBT_OFF  = 666176;   // x^T bf16 [128][4096] (262144 floats)
constexpr int TP_OFF   = 928320;   // 8 * 524288 T partials (16 MB)
constexpr int BM_OFF   = 5122624;  // 2*4096*512 B bitmasks (4 MB)
// end: 6171200 floats ≈ 23.5 MB

__device__ __forceinline__ unsigned short f2bf(float f) {
  unsigned int u = __float_as_uint(f);
  u += 0x7FFFu + ((u >> 16) & 1u);
  return (unsigned short)(u >> 16);
}
__device__ __forceinline__ float bf2f(unsigned short b) {
  return __uint_as_float(((unsigned int)b) << 16);
}
__device__ __forceinline__ float scrub(float v) {
  unsigned int u = __float_as_uint(v);
  return ((u & 0x7F800000u) == 0x7F800000u) ? 0.f : v;
}

// 20 projected vectors + integrated dtype detection.
__global__ __launch_bounds__(128) void k_vvec(const void* __restrict__ xin,
                                              const void* __restrict__ w_irr,
                                              const void* __restrict__ w_sol,
                                              const void* __restrict__ att_irr,
                                              const void* __restrict__ att_sol,
                                              int* __restrict__ flagp,
                                              float* __restrict__ vvec) {
  __shared__ int sdet[128];
  int t = threadIdx.x;
  unsigned int ef = (((const unsigned int*)xin)[t] >> 7) & 0xFFu;
  sdet[t] = (ef >= 100u && ef <= 150u) ? 1 : 0;
  __syncthreads();
  for (int d = 64; d > 0; d >>= 1) { if (t < d) sdet[t] += sdet[t + d]; __syncthreads(); }
  int f = (sdet[0] >= 96) ? 1 : 0;
  if (blockIdx.x == 0 && t == 0) *flagp = f;
  int bx = blockIdx.x;  // b*10 + j*5 + tt
  int b = bx / 10, rem = bx % 10, j = rem / 5, tt = rem % 5;
  const void* Wv = (b == 0 ? w_irr : w_sol);
  const void* Av = (b == 0 ? att_irr : att_sol);
  int i = t;
  float s = 0.f;
  if (f) {
    const unsigned short* Wr = (const unsigned short*)Wv + (size_t)j * 16384 + (size_t)i * 128;
    const unsigned short* Ar = (const unsigned short*)Av + tt * 128;
    for (int o = 0; o < 128; o += 8) {
      uint4 wq = *(const uint4*)(Wr + o);
      unsigned int ww[4] = {wq.x, wq.y, wq.z, wq.w};
      float cf[8];
      if (tt < 4) {
        uint4 aq = *(const uint4*)(Ar + o);
        unsigned int aa[4] = {aq.x, aq.y, aq.z, aq.w};
#pragma unroll
        for (int u = 0; u < 4; ++u) {
          cf[2 * u] = bf2f((unsigned short)(aa[u] & 0xFFFFu));
          cf[2 * u + 1] = bf2f((unsigned short)(aa[u] >> 16));
        }
      } else {
#pragma unroll
        for (int e = 0; e < 8; ++e) cf[e] = 1.0f;
      }
#pragma unroll
      for (int u = 0; u < 4; ++u) {
        s += bf2f((unsigned short)(ww[u] & 0xFFFFu)) * cf[2 * u];
        s += bf2f((unsigned short)(ww[u] >> 16)) * cf[2 * u + 1];
      }
    }
  } else {
    const float* Wr = (const float*)Wv + (size_t)j * 16384 + (size_t)i * 128;
    const float* Ar = (const float*)Av + tt * 128;
    for (int o = 0; o < 128; o += 4) {
      float4 wq = *(const float4*)(Wr + o);
      float4 aq = {1.f, 1.f, 1.f, 1.f};
      if (tt < 4) aq = *(const float4*)(Ar + o);
      s += wq.x * aq.x + wq.y * aq.y + wq.z * aq.z + wq.w * aq.w;
    }
  }
  vvec[bx * 128 + i] = s;
}

// fused: decode x -> LDS; emit xbT (bf16 transpose), np (20 dots/node), src/dst
__global__ __launch_bounds__(256) void k_prep(const void* __restrict__ xin,
                                              const int* __restrict__ flag,
                                              const float* __restrict__ vvec,
                                              unsigned short* __restrict__ xbT,
                                              float* __restrict__ np,
                                              float* __restrict__ srcdst) {
  __shared__ __align__(16) float ldsx[64 * 130];
  __shared__ __align__(16) float ldsv[2560];
  __shared__ float ldsp[4 * 1280];
  __shared__ float npl[1280];
  int f = *flag;
  int t = threadIdx.x, nb = blockIdx.x * 64;
  for (int q = 0; q < 16; ++q) {
    int idx = q * 256 + t;
    int row = idx >> 6, cp = idx & 63;
    float vx, vy;
    if (f) {
      unsigned int u = ((const unsigned int*)xin)[(size_t)(nb + row) * 64 + cp];
      vx = bf2f((unsigned short)(u & 0xFFFFu));
      vy = bf2f((unsigned short)(u >> 16));
    } else {
      float2 v = ((const float2*)xin)[(size_t)(nb + row) * 64 + cp];
      vx = v.x; vy = v.y;
    }
    ldsx[row * 130 + cp * 2] = vx;
    ldsx[row * 130 + cp * 2 + 1] = vy;
  }
  for (int q = 0; q < 10; ++q) { int idx = q * 256 + t; ldsv[idx] = vvec[idx]; }
  __syncthreads();
  for (int q = 0; q < 32; ++q) {
    int idx = q * 256 + t;
    int c = idx >> 6, n = idx & 63;
    xbT[(size_t)c * 4096 + nb + n] = f2bf(ldsx[n * 130 + c]);
  }
  int row = t & 63, qq = t >> 6, i0 = qq * 32;
  float acc[20];
#pragma unroll
  for (int k = 0; k < 20; ++k) acc[k] = 0.f;
  for (int i = i0; i < i0 + 32; i += 2) {
    float2 xv = *(const float2*)&ldsx[row * 130 + i];
#pragma unroll
    for (int k = 0; k < 20; ++k) {
      float2 vk = *(const float2*)&ldsv[k * 128 + i];
      acc[k] += xv.x * vk.x + xv.y * vk.y;
    }
  }
#pragma unroll
  for (int k = 0; k < 20; ++k) ldsp[qq * 1280 + row * 20 + k] = acc[k];
  __syncthreads();
  for (int rep = 0; rep < 5; ++rep) {
    int idx = rep * 256 + t;
    int k = idx >> 6, rr = idx & 63;
    float s = ldsp[rr * 20 + k] + ldsp[1280 + rr * 20 + k] +
              ldsp[2560 + rr * 20 + k] + ldsp[3840 + rr * 20 + k];
    npl[k * 64 + rr] = s;
    np[(size_t)k * 4096 + nb + rr] = s;
  }
  __syncthreads();
  {
    int b = t >> 7, j = (t >> 6) & 1, kind = (t >> 5) & 1, q = t & 31;
    int bl = q * 2;
    int r = j * 2048 + (nb >> 1) + q;
    int kidx = b * 10 + j * 5 + kind * 2;
    float val = npl[kidx * 64 + bl] + npl[(kidx + 1) * 64 + bl + 1];
    srcdst[b * 8192 + kind * 4096 + r] = val;
  }
}

// bitmask compression, 1024 WGs total (was 16384 -> WG-dispatch-rate-bound).
// Each WG emits a contiguous 4 KB chunk: 16 coalesced uint4 loads/thread,
// bytes staged in LDS, stored as uint4. byte j of row r covers cols [8j,8j+8).
__global__ __launch_bounds__(256) void k_mask(const void* __restrict__ Ldown,
                                              const void* __restrict__ Lup,
                                              const int* __restrict__ flag,
                                              unsigned char* __restrict__ bm) {
  __shared__ __align__(16) unsigned char lb[4096];
  int f = *flag;
  int b = blockIdx.y;
  const void* mask = b ? Lup : Ldown;
  int t = threadIdx.x;
  size_t wg = (size_t)blockIdx.x * 4096;  // output byte base
  if (f) {
    const uint4* in4 = (const uint4*)mask;  // 1 uint4 = 8 halfwords = 1 out byte
#pragma unroll
    for (int k = 0; k < 16; ++k) {
      size_t bi = wg + k * 256 + t;
      uint4 v = in4[bi];
      unsigned int by = 0;
      by |= ((v.x & 0xFFFFu) != 0u ? 1u : 0u) << 0;
      by |= ((v.x >> 16) != 0u ? 1u : 0u) << 1;
      by |= ((v.y & 0xFFFFu) != 0u ? 1u : 0u) << 2;
      by |= ((v.y >> 16) != 0u ? 1u : 0u) << 3;
      by |= ((v.z & 0xFFFFu) != 0u ? 1u : 0u) << 4;
      by |= ((v.z >> 16) != 0u ? 1u : 0u) << 5;
      by |= ((v.w & 0xFFFFu) != 0u ? 1u : 0u) << 6;
      by |= ((v.w >> 16) != 0u ? 1u : 0u) << 7;
      lb[k * 256 + t] = (unsigned char)by;
    }
  } else {
    const uint4* in4 = (const uint4*)mask;  // 2 uint4 = 8 floats = 1 out byte
#pragma unroll
    for (int k = 0; k < 16; ++k) {
      size_t bi = wg + k * 256 + t;
      uint4 v0 = in4[2 * bi], v1 = in4[2 * bi + 1];
      unsigned int by = 0;
      by |= (v0.x != 0u ? 1u : 0u) << 0;
      by |= (v0.y != 0u ? 1u : 0u) << 1;
      by |= (v0.z != 0u ? 1u : 0u) << 2;
      by |= (v0.w != 0u ? 1u : 0u) << 3;
      by |= (v1.x != 0u ? 1u : 0u) << 4;
      by |= (v1.y != 0u ? 1u : 0u) << 5;
      by |= (v1.z != 0u ? 1u : 0u) << 6;
      by |= (v1.w != 0u ? 1u : 0u) << 7;
      lb[k * 256 + t] = (unsigned char)by;
    }
  }
  __syncthreads();
  ((uint4*)(bm + (size_t)b * 2097152 + wg))[t] = ((const uint4*)lb)[t];
}

// wave-per-row softmax from compressed bitmask (lane l owns cols [64l,64l+64)),
// 2 rows/wave -> 1024 WGs. Writes rowmax/rowsum + colsum atomics. No CSR.
__global__ __launch_bounds__(256) void k_soft(float* __restrict__ ws) {
  const unsigned char* bm = (const unsigned char*)(ws + BM_OFF);
  int b = blockIdx.y, t = threadIdx.x;
  int wid = t >> 6, l = t & 63;
  const float* srcp = ws + SRC_OFF + b * 8192;
  const float* dstp = srcp + 4096;
#pragma unroll
  for (int rr = 0; rr < 2; ++rr) {
    int r = blockIdx.x * 8 + wid * 2 + rr;
    unsigned long long hm =
        ((const unsigned long long*)(bm + ((size_t)b * 4096 + r) * 512))[l];
    float srcr = srcp[r];
    float ev[8];
    int mv[8];
    int nh = 0;
    float mx = NEG_SENTINEL, sm = 0.f;
    unsigned long long mm = hm;
    while (mm) {
      int bit = __builtin_ctzll(mm); mm &= mm - 1;
      int m = l * 64 + bit;
      float e = srcr + dstp[m];
      e = (e >= 0.f) ? e : 0.01f * e;
      if (nh < 8) { ev[nh] = e; mv[nh] = m; }
      ++nh;
      if (e > mx) { sm = sm * __expf(mx - e) + 1.f; mx = e; }
      else        { sm += __expf(e - mx); }
    }
    for (int d = 1; d < 64; d <<= 1) {
      float om = __shfl_xor(mx, d);
      float os = __shfl_xor(sm, d);
      float M = fmaxf(mx, om);
      sm = sm * __expf(mx - M) + os * __expf(om - M);
      mx = M;
    }
    if (l == 0) {
      ws[RM_OFF + b * 4096 + r] = mx;
      ws[RS_OFF + b * 4096 + r] = sm;
    }
    float inv = 1.0f / sm;
    int cap = (nh < 8) ? nh : 8;
    for (int i = 0; i < cap; ++i)
      atomicAdd(&ws[C_OFF + b * 4096 + mv[i]], __expf(ev[i] - mx) * inv);
    if (nh > 8) {  // overflow fallback (P ~ 1e-9/lane): recompute from mask
      int skip = 8;
      mm = hm;
      while (mm) {
        int bit = __builtin_ctzll(mm); mm &= mm - 1;
        if (skip > 0) { --skip; continue; }
        int m = l * 64 + bit;
        float e = srcr + dstp[m];
        e = (e >= 0.f) ? e : 0.01f * e;
        atomicAdd(&ws[C_OFF + b * 4096 + m], __expf(e - mx) * inv);
      }
    }
  }
}

// c2[m] += c[r]*alpha[r,m], bitmask-driven (no CSR), 2 rows/wave -> 1024 WGs
__global__ __launch_bounds__(256) void k_c2(float* __restrict__ ws) {
  const unsigned char* bm = (const unsigned char*)(ws + BM_OFF);
  int b = blockIdx.y, t = threadIdx.x;
  int wid = t >> 6, l = t & 63;
  const float* srcp = ws + SRC_OFF + b * 8192;
  const float* dstp = srcp + 4096;
#pragma unroll
  for (int rr = 0; rr < 2; ++rr) {
    int r = blockIdx.x * 8 + wid * 2 + rr;
    unsigned long long hm =
        ((const unsigned long long*)(bm + ((size_t)b * 4096 + r) * 512))[l];
    float srcr = srcp[r];
    float rm = ws[RM_OFF + b * 4096 + r];
    float w = ws[C_OFF + b * 4096 + r] / ws[RS_OFF + b * 4096 + r];
    while (hm) {
      int bit = __builtin_ctzll(hm); hm &= hm - 1;
      int m = l * 64 + bit;
      float e = srcr + dstp[m];
      e = (e >= 0.f) ? e : 0.01f * e;
      atomicAdd(&ws[C2_OFF + b * 4096 + m], __expf(e - rm) * w);
    }
  }
}

__global__ __launch_bounds__(256) void k_scalar(float* __restrict__ ws) {
  int b = blockIdx.x, t = threadIdx.x;
  const float* cb  = ws + C_OFF  + b * 4096;
  const float* c2b = ws + C2_OFF + b * 4096;
  const float* hr0 = ws + NP_OFF + (b * 10 + 4) * 4096;
  const float* hr1 = ws + NP_OFF + (b * 10 + 9) * 4096;
  double acc = 0.0;
  for (int m = t; m < 4096; m += 256)
    acc += (double)scrub(cb[m]) * (double)scrub(hr0[m]) +
           (double)scrub(c2b[m]) * (double)scrub(hr1[m]);
  __shared__ double sd[256];
  sd[t] = acc;
  __syncthreads();
  for (int s = 128; s > 0; s >>= 1) { if (t < s) sd[t] += sd[t + s]; __syncthreads(); }
  if (t == 0) atomicAdd(&ws[SC_OFF], (float)sd[0]);
}

// T = P @ x: 512 blocks (64 M-tiles x 8 K-splits), pipelined, partial stores
__global__ __launch_bounds__(256) void k_gemm1(const void* __restrict__ P,
                                               const unsigned short* __restrict__ xbT,
                                               const int* __restrict__ flag,
                                               float* __restrict__ TP) {
  __shared__ __align__(16) unsigned short a_lds[64 * 40];
  __shared__ __align__(16) unsigned short b_lds[128 * 40];
  int f = *flag;
  const int mt = blockIdx.x & 63, ks = blockIdx.x >> 6;
  const int mb = mt * 64;
  const int t = threadIdx.x;
  const int w = t >> 6, l = t & 63, quad = l >> 4, lr = l & 15;
  f32x4 acc[8] = {};
  const int arow = t >> 2, akq = (t & 3) << 3;
  const int bn = t >> 1, bh = (t & 1) << 4;
  const int k0 = ks * 512;
  uint4 aU, bU0, bU1;
#define LOADT(IT)                                                              \
  {                                                                            \
    const int kb = k0 + (IT) * 32;                                             \
    if (f) {                                                                   \
      aU = *(const uint4*)((const unsigned short*)P +                          \
                           (size_t)(mb + arow) * 4096 + kb + akq);             \
    } else {                                                                   \
      const float* pa = (const float*)P + (size_t)(mb + arow) * 4096 + kb + akq; \
      float4 f0 = *(const float4*)pa;                                          \
      float4 f1 = *(const float4*)(pa + 4);                                    \
      unsigned short u[8] = {f2bf(f0.x), f2bf(f0.y), f2bf(f0.z), f2bf(f0.w),   \
                             f2bf(f1.x), f2bf(f1.y), f2bf(f1.z), f2bf(f1.w)};  \
      aU = *(const uint4*)u;                                                   \
    }                                                                          \
    const unsigned short* src = xbT + (size_t)bn * 4096 + kb + bh;             \
    bU0 = *(const uint4*)src;                                                  \
    bU1 = *(const uint4*)(src + 8);                                            \
  }
  LOADT(0);
  for (int it = 0; it < 16; ++it) {
    *(uint4*)&a_lds[arow * 40 + akq] = aU;
    *(uint4*)&b_lds[bn * 40 + bh] = bU0;
    *(uint4*)&b_lds[bn * 40 + bh + 8] = bU1;
    __syncthreads();
    if (it < 15) LOADT(it + 1);
    short8b af = *(short8b*)&a_lds[(w * 16 + lr) * 40 + quad * 8];
#pragma unroll
    for (int nt = 0; nt < 8; ++nt) {
      short8b bf = *(short8b*)&b_lds[(nt * 16 + lr) * 40 + quad * 8];
      acc[nt] = __builtin_amdgcn_mfma_f32_16x16x32_bf16(af, bf, acc[nt], 0, 0, 0);
    }
    if (it < 15) __syncthreads();
  }
#undef LOADT
  float* Tp = TP + (size_t)ks * 524288;
#pragma unroll
  for (int nt = 0; nt < 8; ++nt)
#pragma unroll
    for (int rr = 0; rr < 4; ++rr) {
      int row = mb + w * 16 + quad * 4 + rr;
      int col = nt * 16 + lr;
      Tp[(size_t)row * 128 + col] = acc[nt][rr];
    }
}

// out = scalar + (sum of 8 T partials) @ W_har; 256 blocks x 16 rows
__global__ __launch_bounds__(256) void k_gemm2(const float* __restrict__ TP,
                                               const void* __restrict__ W,
                                               const float* __restrict__ ws,
                                               void* __restrict__ outv) {
  __shared__ float tl[16 * 128];
  int f = ((const int*)ws)[FLAG_I];
  int t = threadIdx.x;
  int rb = blockIdx.x * 16;
  for (int q = 0; q < 2; ++q) {
    int vi = q * 256 + t;
    size_t base = (size_t)rb * 128 + (size_t)vi * 4;
    float4 s = {0.f, 0.f, 0.f, 0.f};
#pragma unroll
    for (int p = 0; p < 8; ++p) {
      float4 v = *(const float4*)&TP[(size_t)p * 524288 + base];
      s.x += v.x; s.y += v.y; s.z += v.z; s.w += v.w;
    }
    *(float4*)&tl[vi * 4] = s;
  }
  __syncthreads();
  int col = t & 127, rg = t >> 7;
  int r0 = rg * 8;
  float acc[8] = {};
  for (int k = 0; k < 128; k += 4) {
    float w0, w1, w2, w3;
    if (f) {
      const unsigned short* W16 = (const unsigned short*)W;
      w0 = bf2f(W16[(k + 0) * 128 + col]); w1 = bf2f(W16[(k + 1) * 128 + col]);
      w2 = bf2f(W16[(k + 2) * 128 + col]); w3 = bf2f(W16[(k + 3) * 128 + col]);
    } else {
      const float* W32 = (const float*)W;
      w0 = W32[(k + 0) * 128 + col]; w1 = W32[(k + 1) * 128 + col];
      w2 = W32[(k + 2) * 128 + col]; w3 = W32[(k + 3) * 128 + col];
    }
#pragma unroll
    for (int rr = 0; rr < 8; ++rr) {
      float4 tv = *(const float4*)&tl[(r0 + rr) * 128 + k];
      acc[rr] += tv.x * w0 + tv.y * w1 + tv.z * w2 + tv.w * w3;
    }
  }
  float s = scrub(ws[SC_OFF]);
#pragma unroll
  for (int rr = 0; rr < 8; ++rr) {
    size_t oi = (size_t)(rb + r0 + rr) * 128 + col;
    float v = s + acc[rr];
    if (f) ((unsigned short*)outv)[oi] = f2bf(v);
    else   ((float*)outv)[oi] = v;
  }
}

extern "C" void kernel_launch(void* const* d_in, const int* in_sizes, int n_in,
                              void* d_out, int out_size, void* d_ws, size_t ws_size,
                              hipStream_t stream) {
  const void* x       = d_in[0];
  const void* Lup     = d_in[1];
  const void* Ldown   = d_in[2];
  const void* P       = d_in[3];
  const void* w_irr   = d_in[4];
  const void* w_sol   = d_in[5];
  const void* w_har   = d_in[6];
  const void* att_irr = d_in[7];
  const void* att_sol = d_in[8];
  float* ws = (float*)d_ws;

  hipMemsetAsync(d_ws, 0, (size_t)ZERO_N * sizeof(float), stream);
  k_vvec  <<<20, 128, 0, stream>>>(x, w_irr, w_sol, att_irr, att_sol,
                                   (int*)ws + FLAG_I, ws + V_OFF);
  k_prep  <<<64, 256, 0, stream>>>(x, (int*)ws + FLAG_I, ws + V_OFF,
                                   (unsigned short*)(ws + XBT_OFF), ws + NP_OFF,
                                   ws + SRC_OFF);
  k_gemm1 <<<512, 256, 0, stream>>>(P, (const unsigned short*)(ws + XBT_OFF),
                                    (int*)ws + FLAG_I, ws + TP_OFF);
  k_mask  <<<dim3(512, 2), 256, 0, stream>>>(Ldown, Lup, (int*)ws + FLAG_I,
                                             (unsigned char*)(ws + BM_OFF));
  k_soft  <<<dim3(512, 2), 256, 0, stream>>>(ws);
  k_c2    <<<dim3(512, 2), 256, 0, stream>>>(ws);
  k_scalar<<<2, 256, 0, stream>>>(ws);
  k_gemm2 <<<256, 256, 0, stream>>>(ws + TP_OFF, w_har, ws, d_out);
}